// Round 1
// baseline (840.590 us; speedup 1.0000x reference)
//
#include <hip/hip_runtime.h>
#include <hip/hip_bf16.h>

#define DEV __device__ __forceinline__

DEV float lrelu(float x) { return x > 0.f ? x : 0.2f * x; }

__global__ void zero_i32(int* __restrict__ p, int n) {
    int i = blockIdx.x * 256 + threadIdx.x;
    if (i < n) p[i] = 0;
}

__global__ void hist_kernel(const int* __restrict__ ei, int* __restrict__ deg, int E) {
    int e = blockIdx.x * 256 + threadIdx.x;
    if (e < E) atomicAdd(&deg[ei[E + e]], 1);
}

// one block, 1024 threads: exclusive scan of deg -> row_start[0..n], copy to cursor
__global__ void scan_kernel(const int* __restrict__ deg, int* __restrict__ row_start,
                            int* __restrict__ cursor, int n) {
    __shared__ int part[1024];
    int tid = threadIdx.x;
    int chunk = (n + 1023) >> 10;
    int begin = tid * chunk;
    int end = begin + chunk; if (end > n) end = n;
    int s = 0;
    for (int i = begin; i < end; ++i) s += deg[i];
    part[tid] = s;
    __syncthreads();
    for (int off = 1; off < 1024; off <<= 1) {
        int t = (tid >= off) ? part[tid - off] : 0;
        __syncthreads();
        part[tid] += t;
        __syncthreads();
    }
    int run = part[tid] - s;  // exclusive prefix
    for (int i = begin; i < end; ++i) {
        row_start[i] = run; cursor[i] = run; run += deg[i];
    }
    if (tid == 1023) row_start[n] = run;
}

__global__ void scatter_kernel(const int* __restrict__ ei, int* __restrict__ cursor,
                               int* __restrict__ col, int E) {
    int e = blockIdx.x * 256 + threadIdx.x;
    if (e < E) {
        int s = ei[e], d = ei[E + e];
        int pos = atomicAdd(&cursor[d], 1);
        col[pos] = s;
    }
}

// X[n,128] @ W[128,128] -> xw[n,128]; fused alpha_src/dst = sum_c xw*a over each head's 32 cols.
// 128 threads: thread t owns output column t for 8 nodes. x rows staged in LDS transposed [k][j].
__global__ __launch_bounds__(128)
void gemm_alpha_kernel(const float* __restrict__ X, const float* __restrict__ W,
                       const float* __restrict__ a_src, const float* __restrict__ a_dst,
                       float* __restrict__ xw, float* __restrict__ asrc,
                       float* __restrict__ adst, int n) {
    __shared__ float xs[128 * 8];  // xs[k*8 + j]
    int tid = threadIdx.x;
    int i0 = blockIdx.x * 8;
    for (int r = 0; r < 8; ++r) {
        int row = i0 + r;
        xs[tid * 8 + r] = (row < n) ? X[(size_t)row * 128 + tid] : 0.f;
    }
    __syncthreads();
    float acc[8] = {0.f, 0.f, 0.f, 0.f, 0.f, 0.f, 0.f, 0.f};
#pragma unroll 8
    for (int k = 0; k < 128; ++k) {
        float w = W[k * 128 + tid];
        const float4* xp = (const float4*)&xs[k * 8];
        float4 xa = xp[0], xb = xp[1];
        acc[0] = fmaf(xa.x, w, acc[0]);
        acc[1] = fmaf(xa.y, w, acc[1]);
        acc[2] = fmaf(xa.z, w, acc[2]);
        acc[3] = fmaf(xa.w, w, acc[3]);
        acc[4] = fmaf(xb.x, w, acc[4]);
        acc[5] = fmaf(xb.y, w, acc[5]);
        acc[6] = fmaf(xb.z, w, acc[6]);
        acc[7] = fmaf(xb.w, w, acc[7]);
    }
    float as_t = a_src[tid], ad_t = a_dst[tid];
    int h = tid >> 5;
#pragma unroll
    for (int j = 0; j < 8; ++j) {
        int row = i0 + j;
        if (row >= n) break;
        float a = acc[j];
        xw[(size_t)row * 128 + tid] = a;
        float v1 = a * as_t, v2 = a * ad_t;
#pragma unroll
        for (int off = 16; off > 0; off >>= 1) {
            v1 += __shfl_xor(v1, off);   // xor<32 stays within the 32-lane head group
            v2 += __shfl_xor(v2, off);
        }
        if ((tid & 31) == 0) {
            asrc[row * 4 + h] = v1;
            adst[row * 4 + h] = v2;
        }
    }
}

// One node per 128 threads (2 nodes/block). thread t = h*32+c.
// Unnormalized accumulation + denominator; self-loop handled analytically.
__global__ __launch_bounds__(256)
void aggregate_kernel(const float* __restrict__ xw, const float* __restrict__ asrc,
                      const float* __restrict__ adst, const int* __restrict__ col,
                      const int* __restrict__ rs, const float* __restrict__ bias,
                      float* __restrict__ out, int n) {
    int tid = threadIdx.x;
    int i = blockIdx.x * 2 + (tid >> 7);
    if (i >= n) return;
    int t = tid & 127;
    int h = t >> 5;
    float ad = adst[i * 4 + h];
    float e_self = lrelu(asrc[i * 4 + h] + ad);
    int beg = rs[i], end = rs[i + 1];
    float m = e_self;
    for (int j = beg; j < end; ++j) {
        int s = col[j];
        float e = lrelu(asrc[s * 4 + h] + ad);
        m = fmaxf(m, e);
    }
    float wsum = __expf(e_self - m);
    float acc = wsum * xw[(size_t)i * 128 + t];
    for (int j = beg; j < end; ++j) {
        int s = col[j];
        float e = lrelu(asrc[s * 4 + h] + ad);
        float wgt = __expf(e - m);
        wsum += wgt;
        acc = fmaf(wgt, xw[(size_t)s * 128 + t], acc);
    }
    float v = acc / wsum + bias[t];
    out[(size_t)i * 128 + t] = v > 0.f ? v : __expf(v) - 1.f;  // ELU
}

// out[i] = sum_t h[i,t]*Wr[t] + br ; one node per 64-lane wave, 4 nodes/block
__global__ __launch_bounds__(256)
void head_kernel(const float* __restrict__ hin, const float* __restrict__ Wr,
                 const float* __restrict__ br, float* __restrict__ out, int n) {
    int tid = threadIdx.x;
    int i = blockIdx.x * 4 + (tid >> 6);
    if (i >= n) return;
    int l = tid & 63;
    float v = hin[(size_t)i * 128 + l] * Wr[l] + hin[(size_t)i * 128 + 64 + l] * Wr[64 + l];
#pragma unroll
    for (int off = 32; off > 0; off >>= 1) v += __shfl_xor(v, off);
    if (l == 0) out[i] = v + br[0];
}

extern "C" void kernel_launch(void* const* d_in, const int* in_sizes, int n_in,
                              void* d_out, int out_size, void* d_ws, size_t ws_size,
                              hipStream_t stream) {
    const float* x   = (const float*)d_in[0];
    const int*   ei  = (const int*)d_in[1];
    const float* W0  = (const float*)d_in[2];
    const float* as0 = (const float*)d_in[3];
    const float* ad0 = (const float*)d_in[4];
    const float* b0  = (const float*)d_in[5];
    const float* W1  = (const float*)d_in[6];
    const float* as1 = (const float*)d_in[7];
    const float* ad1 = (const float*)d_in[8];
    const float* b1  = (const float*)d_in[9];
    const float* Wr  = (const float*)d_in[10];
    const float* br  = (const float*)d_in[11];
    float* out = (float*)d_out;

    const int N = in_sizes[0] / 128;
    const int E = in_sizes[1] / 2;

    char* w = (char*)d_ws;
    size_t off = 0;
    auto alloc = [&](size_t bytes) -> void* {
        void* p = w + off;
        off += (bytes + 255) & ~size_t(255);
        return p;
    };
    float* bufA   = (float*)alloc((size_t)N * 128 * 4);  // xw
    float* bufB   = (float*)alloc((size_t)N * 128 * 4);  // layer output h
    float* asrc   = (float*)alloc((size_t)N * 4 * 4);
    float* adst   = (float*)alloc((size_t)N * 4 * 4);
    int*   deg    = (int*)alloc((size_t)N * 4);
    int*   rs     = (int*)alloc((size_t)(N + 1) * 4);
    int*   cursor = (int*)alloc((size_t)N * 4);
    int*   col    = (int*)alloc((size_t)E * 4);

    // CSR build (shared by both layers)
    zero_i32<<<(N + 255) / 256, 256, 0, stream>>>(deg, N);
    hist_kernel<<<(E + 255) / 256, 256, 0, stream>>>(ei, deg, E);
    scan_kernel<<<1, 1024, 0, stream>>>(deg, rs, cursor, N);
    scatter_kernel<<<(E + 255) / 256, 256, 0, stream>>>(ei, cursor, col, E);

    // Layer 0
    gemm_alpha_kernel<<<(N + 7) / 8, 128, 0, stream>>>(x, W0, as0, ad0, bufA, asrc, adst, N);
    aggregate_kernel<<<(N + 1) / 2, 256, 0, stream>>>(bufA, asrc, adst, col, rs, b0, bufB, N);
    // Layer 1
    gemm_alpha_kernel<<<(N + 7) / 8, 128, 0, stream>>>(bufB, W1, as1, ad1, bufA, asrc, adst, N);
    aggregate_kernel<<<(N + 1) / 2, 256, 0, stream>>>(bufA, asrc, adst, col, rs, b1, bufB, N);
    // Regression head
    head_kernel<<<(N + 3) / 4, 256, 0, stream>>>(bufB, Wr, br, out, N);
}

// Round 2
// 825.039 us; speedup vs baseline: 1.0188x; 1.0188x over previous
//
#include <hip/hip_runtime.h>
#include <hip/hip_bf16.h>

#define DEV __device__ __forceinline__

DEV float lrelu(float x) { return x > 0.f ? x : 0.2f * x; }

__global__ void zero_i32(int* __restrict__ p, int n) {
    int i = blockIdx.x * 256 + threadIdx.x;
    if (i < n) p[i] = 0;
}

__global__ void hist_kernel(const int* __restrict__ ei, int* __restrict__ deg, int E) {
    int e = blockIdx.x * 256 + threadIdx.x;
    if (e < E) atomicAdd(&deg[ei[E + e]], 1);
}

// one block, 1024 threads: exclusive scan of deg -> row_start[0..n], copy to cursor
__global__ void scan_kernel(const int* __restrict__ deg, int* __restrict__ row_start,
                            int* __restrict__ cursor, int n) {
    __shared__ int part[1024];
    int tid = threadIdx.x;
    int chunk = (n + 1023) >> 10;
    int begin = tid * chunk;
    int end = begin + chunk; if (end > n) end = n;
    int s = 0;
    for (int i = begin; i < end; ++i) s += deg[i];
    part[tid] = s;
    __syncthreads();
    for (int off = 1; off < 1024; off <<= 1) {
        int t = (tid >= off) ? part[tid - off] : 0;
        __syncthreads();
        part[tid] += t;
        __syncthreads();
    }
    int run = part[tid] - s;  // exclusive prefix
    for (int i = begin; i < end; ++i) {
        row_start[i] = run; cursor[i] = run; run += deg[i];
    }
    if (tid == 1023) row_start[n] = run;
}

__global__ void scatter_kernel(const int* __restrict__ ei, int* __restrict__ cursor,
                               int* __restrict__ col, int E) {
    int e = blockIdx.x * 256 + threadIdx.x;
    if (e < E) {
        int s = ei[e], d = ei[E + e];
        int pos = atomicAdd(&cursor[d], 1);
        col[pos] = s;
    }
}

// GEMM v3: thread-per-node. X rows staged in LDS (stride 129 -> conflict-free
// broadcastless b32 reads, bank = (lane + k) % 32, 2-way alias only).
// W[k*128+c] addresses are wave-uniform -> compiler emits s_load (scalar pipe),
// leaving VALU pure FMA: 16384 fma/thread.
__global__ __launch_bounds__(64)
void gemm_alpha_v3(const float* __restrict__ X, const float* __restrict__ W,
                   const float* __restrict__ a_src, const float* __restrict__ a_dst,
                   float* __restrict__ xw, float* __restrict__ asrc,
                   float* __restrict__ adst, int n) {
    __shared__ float xs[64 * 129];
    int t = threadIdx.x;
    int n0 = blockIdx.x * 64;
    for (int idx = t; idx < 64 * 32; idx += 64) {
        int r = idx >> 5, q = idx & 31;
        int row = n0 + r;
        float4 v = (row < n) ? *(const float4*)&X[(size_t)row * 128 + q * 4]
                             : make_float4(0.f, 0.f, 0.f, 0.f);
        float* dst = &xs[r * 129 + q * 4];
        dst[0] = v.x; dst[1] = v.y; dst[2] = v.z; dst[3] = v.w;
    }
    __syncthreads();
    int node = n0 + t;
    if (node >= n) return;
    const float* xr = &xs[t * 129];
#pragma unroll
    for (int h = 0; h < 4; ++h) {
        float vs = 0.f, vd = 0.f;
        for (int cc2 = 0; cc2 < 4; ++cc2) {
            int cbase = h * 32 + cc2 * 8;
            float acc[8] = {0.f, 0.f, 0.f, 0.f, 0.f, 0.f, 0.f, 0.f};
#pragma unroll 8
            for (int k = 0; k < 128; ++k) {
                float x = xr[k];
                const float* wr = &W[k * 128 + cbase];  // wave-uniform -> s_load
#pragma unroll
                for (int c = 0; c < 8; ++c) acc[c] = fmaf(x, wr[c], acc[c]);
            }
            float4 o1 = make_float4(acc[0], acc[1], acc[2], acc[3]);
            float4 o2 = make_float4(acc[4], acc[5], acc[6], acc[7]);
            *(float4*)&xw[(size_t)node * 128 + cbase] = o1;
            *(float4*)&xw[(size_t)node * 128 + cbase + 4] = o2;
#pragma unroll
            for (int c = 0; c < 8; ++c) {
                vs = fmaf(acc[c], a_src[cbase + c], vs);
                vd = fmaf(acc[c], a_dst[cbase + c], vd);
            }
        }
        asrc[node * 4 + h] = vs;
        adst[node * 4 + h] = vd;
    }
}

// Aggregate v2: one block (256 thr) per dst node. Chunked online softmax:
//   P1: 64 edges/chunk, 4 lanes/edge (one per head) compute logits once,
//       shuffle-reduce max per head.
//   P2: exp weights -> LDS, shuffle-reduce sum per head.
//   U : 4 threads fold chunk into running (m, wsum) with rescale factor sc.
//   P3: 8 edge-groups x 32 lanes, coalesced float4 xw-row gather + fma into
//       per-group partial accumulators (rescaled by sc each chunk).
// Self-loop handled analytically: init m=e_self, wsum=1, acc(g0)=xw[i].
__global__ __launch_bounds__(256)
void aggregate_v2(const float* __restrict__ xw, const float* __restrict__ asrc,
                  const float* __restrict__ adst, const int* __restrict__ col,
                  const int* __restrict__ rs, const float* __restrict__ bias,
                  float* __restrict__ out, int n) {
    __shared__ float w_lds[64 * 4];
    __shared__ int   s_lds[64];
    __shared__ float wm[16], ws[16];
    __shared__ float mrun_s[4], wsum_s[4], sc_s[4], tmpm[4];
    __shared__ float accbuf[7 * 128];

    int i = blockIdx.x;
    if (i >= n) return;
    int t = threadIdx.x;
    int h4 = t & 3;          // logit role: head
    int jj = t >> 2;         // logit role: edge slot in chunk [0,64)
    int g  = t >> 5;         // accumulate role: edge group [0,8)
    int c0 = (t & 31) * 4;   // accumulate role: channel base
    int hA = (t & 31) >> 3;  // accumulate role: head of c0

    int beg = rs[i], end = rs[i + 1];
    float ad_l = adst[i * 4 + h4];

    if (t < 4) {
        float es = lrelu(asrc[i * 4 + t] + adst[i * 4 + t]);
        mrun_s[t] = es;
        wsum_s[t] = 1.f;
    }
    float4 acc = make_float4(0.f, 0.f, 0.f, 0.f);
    if (g == 0) acc = *(const float4*)&xw[(size_t)i * 128 + c0];

    __syncthreads();

    for (int ce = beg; ce < end; ce += 64) {
        int nc = end - ce; if (nc > 64) nc = 64;
        // P1: logits
        float e; int s = 0;
        if (jj < nc) {
            s = col[ce + jj];
            e = lrelu(asrc[s * 4 + h4] + ad_l);
        } else {
            e = -3.0e38f;
        }
        float mv = e;
        mv = fmaxf(mv, __shfl_xor(mv, 4));
        mv = fmaxf(mv, __shfl_xor(mv, 8));
        mv = fmaxf(mv, __shfl_xor(mv, 16));
        mv = fmaxf(mv, __shfl_xor(mv, 32));
        if ((t & 63) < 4) wm[(t >> 6) * 4 + h4] = mv;
        __syncthreads();  // B1
        // P2: weights
        float m_old = mrun_s[h4];
        float chm = fmaxf(fmaxf(wm[h4], wm[4 + h4]), fmaxf(wm[8 + h4], wm[12 + h4]));
        float newm = fmaxf(m_old, chm);
        float wv = __expf(e - newm);  // invalid lanes -> exp(-huge) = 0
        w_lds[jj * 4 + h4] = wv;
        float sv = wv;
        sv += __shfl_xor(sv, 4);
        sv += __shfl_xor(sv, 8);
        sv += __shfl_xor(sv, 16);
        sv += __shfl_xor(sv, 32);
        if ((t & 63) < 4) ws[(t >> 6) * 4 + h4] = sv;
        if (t < 4) {              // jj==0 lanes: h4 == t
            tmpm[t] = newm;
            sc_s[t] = __expf(m_old - newm);
        }
        if (h4 == 0 && jj < nc) s_lds[jj] = s;
        __syncthreads();  // B2
        // U: fold chunk into running state
        if (t < 4) {
            float csum = ws[t] + ws[4 + t] + ws[8 + t] + ws[12 + t];
            wsum_s[t] = wsum_s[t] * sc_s[t] + csum;
            mrun_s[t] = tmpm[t];
        }
        // P3: gather + accumulate
        float scA = sc_s[hA];
        acc.x *= scA; acc.y *= scA; acc.z *= scA; acc.w *= scA;
        for (int j2 = g; j2 < nc; j2 += 8) {
            int s2 = s_lds[j2];
            float wgt = w_lds[j2 * 4 + hA];
            float4 v = *(const float4*)&xw[(size_t)s2 * 128 + c0];
            acc.x = fmaf(wgt, v.x, acc.x);
            acc.y = fmaf(wgt, v.y, acc.y);
            acc.z = fmaf(wgt, v.z, acc.z);
            acc.w = fmaf(wgt, v.w, acc.w);
        }
        __syncthreads();  // B3: protect LDS before next chunk's P1/P2 writes
    }

    if (g > 0) *(float4*)&accbuf[(g - 1) * 128 + c0] = acc;
    __syncthreads();
    if (t < 32) {
        float4 tot = acc;
#pragma unroll
        for (int q = 0; q < 7; ++q) {
            float4 v = *(const float4*)&accbuf[q * 128 + c0];
            tot.x += v.x; tot.y += v.y; tot.z += v.z; tot.w += v.w;
        }
        float inv = 1.f / wsum_s[hA];
        float4 bv = *(const float4*)&bias[c0];
        float4 r;
        float u;
        u = tot.x * inv + bv.x; r.x = u > 0.f ? u : __expf(u) - 1.f;
        u = tot.y * inv + bv.y; r.y = u > 0.f ? u : __expf(u) - 1.f;
        u = tot.z * inv + bv.z; r.z = u > 0.f ? u : __expf(u) - 1.f;
        u = tot.w * inv + bv.w; r.w = u > 0.f ? u : __expf(u) - 1.f;
        *(float4*)&out[(size_t)i * 128 + c0] = r;
    }
}

// out[i] = sum_t h[i,t]*Wr[t] + br ; one node per 64-lane wave, 4 nodes/block
__global__ __launch_bounds__(256)
void head_kernel(const float* __restrict__ hin, const float* __restrict__ Wr,
                 const float* __restrict__ br, float* __restrict__ out, int n) {
    int tid = threadIdx.x;
    int i = blockIdx.x * 4 + (tid >> 6);
    if (i >= n) return;
    int l = tid & 63;
    float v = hin[(size_t)i * 128 + l] * Wr[l] + hin[(size_t)i * 128 + 64 + l] * Wr[64 + l];
#pragma unroll
    for (int off = 32; off > 0; off >>= 1) v += __shfl_xor(v, off);
    if (l == 0) out[i] = v + br[0];
}

extern "C" void kernel_launch(void* const* d_in, const int* in_sizes, int n_in,
                              void* d_out, int out_size, void* d_ws, size_t ws_size,
                              hipStream_t stream) {
    const float* x   = (const float*)d_in[0];
    const int*   ei  = (const int*)d_in[1];
    const float* W0  = (const float*)d_in[2];
    const float* as0 = (const float*)d_in[3];
    const float* ad0 = (const float*)d_in[4];
    const float* b0  = (const float*)d_in[5];
    const float* W1  = (const float*)d_in[6];
    const float* as1 = (const float*)d_in[7];
    const float* ad1 = (const float*)d_in[8];
    const float* b1  = (const float*)d_in[9];
    const float* Wr  = (const float*)d_in[10];
    const float* br  = (const float*)d_in[11];
    float* out = (float*)d_out;

    const int N = in_sizes[0] / 128;
    const int E = in_sizes[1] / 2;

    char* w = (char*)d_ws;
    size_t off = 0;
    auto alloc = [&](size_t bytes) -> void* {
        void* p = w + off;
        off += (bytes + 255) & ~size_t(255);
        return p;
    };
    float* bufA   = (float*)alloc((size_t)N * 128 * 4);  // xw
    float* bufB   = (float*)alloc((size_t)N * 128 * 4);  // layer output h
    float* asrc   = (float*)alloc((size_t)N * 4 * 4);
    float* adst   = (float*)alloc((size_t)N * 4 * 4);
    int*   deg    = (int*)alloc((size_t)N * 4);
    int*   rs     = (int*)alloc((size_t)(N + 1) * 4);
    int*   cursor = (int*)alloc((size_t)N * 4);
    int*   col    = (int*)alloc((size_t)E * 4);

    // CSR build (shared by both layers)
    zero_i32<<<(N + 255) / 256, 256, 0, stream>>>(deg, N);
    hist_kernel<<<(E + 255) / 256, 256, 0, stream>>>(ei, deg, E);
    scan_kernel<<<1, 1024, 0, stream>>>(deg, rs, cursor, N);
    scatter_kernel<<<(E + 255) / 256, 256, 0, stream>>>(ei, cursor, col, E);

    int gblk = (N + 63) / 64;
    // Layer 0
    gemm_alpha_v3<<<gblk, 64, 0, stream>>>(x, W0, as0, ad0, bufA, asrc, adst, N);
    aggregate_v2<<<N, 256, 0, stream>>>(bufA, asrc, adst, col, rs, b0, bufB, N);
    // Layer 1
    gemm_alpha_v3<<<gblk, 64, 0, stream>>>(bufB, W1, as1, ad1, bufA, asrc, adst, N);
    aggregate_v2<<<N, 256, 0, stream>>>(bufA, asrc, adst, col, rs, b1, bufB, N);
    // Regression head
    head_kernel<<<(N + 3) / 4, 256, 0, stream>>>(bufB, Wr, br, out, N);
}

// Round 3
// 545.473 us; speedup vs baseline: 1.5410x; 1.5125x over previous
//
#include <hip/hip_runtime.h>
#include <hip/hip_bf16.h>

#define DEV __device__ __forceinline__

DEV float lrelu(float x) { return x > 0.f ? x : 0.2f * x; }
DEV float elu(float x)   { return x > 0.f ? x : __expf(x) - 1.f; }

__global__ void zero_i32(int* __restrict__ p, int n) {
    int i = blockIdx.x * 256 + threadIdx.x;
    if (i < n) p[i] = 0;
}

__global__ void hist_kernel(const int* __restrict__ ei, int* __restrict__ deg, int E) {
    int e = blockIdx.x * 256 + threadIdx.x;
    if (e < E) atomicAdd(&deg[ei[E + e]], 1);
}

// one block, 1024 threads: exclusive scan of deg -> row_start[0..n], copy to cursor
__global__ void scan_kernel(const int* __restrict__ deg, int* __restrict__ row_start,
                            int* __restrict__ cursor, int n) {
    __shared__ int part[1024];
    int tid = threadIdx.x;
    int chunk = (n + 1023) >> 10;
    int begin = tid * chunk;
    int end = begin + chunk; if (end > n) end = n;
    int s = 0;
    for (int i = begin; i < end; ++i) s += deg[i];
    part[tid] = s;
    __syncthreads();
    for (int off = 1; off < 1024; off <<= 1) {
        int t = (tid >= off) ? part[tid - off] : 0;
        __syncthreads();
        part[tid] += t;
        __syncthreads();
    }
    int run = part[tid] - s;  // exclusive prefix
    for (int i = begin; i < end; ++i) {
        row_start[i] = run; cursor[i] = run; run += deg[i];
    }
    if (tid == 1023) row_start[n] = run;
}

__global__ void scatter_kernel(const int* __restrict__ ei, int* __restrict__ cursor,
                               int* __restrict__ col, int E) {
    int e = blockIdx.x * 256 + threadIdx.x;
    if (e < E) {
        int s = ei[e], d = ei[E + e];
        int pos = atomicAdd(&cursor[d], 1);
        col[pos] = s;
    }
}

// GEMM v4: 256 threads, 64-node x 128-col tile, K staged in chunks of 32.
// Thread (rg=t>>4, cg=t&15) computes rows rg*4..+3 x cols cg*8..+7 (acc 4x8).
// Xs transposed [k][row] (stride 68: read banks 4(k+rg), 4 distinct addrs,
// 16-way broadcast -> free). Ws [k][col] stride 132 with +4-float offset for
// cg>=8 so the 16 b128 read starts cover 8 distinct bank groups (2-way = free).
__global__ __launch_bounds__(256)
void gemm_alpha_v4(const float* __restrict__ X, const float* __restrict__ W,
                   const float* __restrict__ a_src, const float* __restrict__ a_dst,
                   float* __restrict__ xw, float* __restrict__ asrc,
                   float* __restrict__ adst, int n) {
    __shared__ float Xs[32][68];
    __shared__ float Ws[32][132];
    int t = threadIdx.x;
    int n0 = blockIdx.x * 64;
    int rg = t >> 4;
    int cg = t & 15;
    int q0 = cg * 8 + ((cg >= 8) ? 4 : 0);
    float acc[4][8];
#pragma unroll
    for (int r = 0; r < 4; ++r)
#pragma unroll
        for (int c = 0; c < 8; ++c) acc[r][c] = 0.f;

    for (int k0 = 0; k0 < 128; k0 += 32) {
        // stage X tile (64 rows x 32 k), transposed into Xs[k][row]
#pragma unroll
        for (int it = 0; it < 2; ++it) {
            int idx = t + it * 256;
            int row = idx >> 3, kq = idx & 7;
            int gr = n0 + row;
            float4 v = make_float4(0.f, 0.f, 0.f, 0.f);
            if (gr < n) v = *(const float4*)&X[(size_t)gr * 128 + k0 + kq * 4];
            Xs[kq * 4 + 0][row] = v.x;
            Xs[kq * 4 + 1][row] = v.y;
            Xs[kq * 4 + 2][row] = v.z;
            Xs[kq * 4 + 3][row] = v.w;
        }
        // stage W chunk (32 k x 128 c)
#pragma unroll
        for (int it = 0; it < 4; ++it) {
            int idx = t + it * 256;
            int k = idx >> 5, cq = idx & 31;
            float4 v = *(const float4*)&W[(size_t)(k0 + k) * 128 + cq * 4];
            *(float4*)&Ws[k][cq * 4 + ((cq >= 16) ? 4 : 0)] = v;
        }
        __syncthreads();
#pragma unroll 4
        for (int k = 0; k < 32; ++k) {
            float4 xv = *(const float4*)&Xs[k][rg * 4];
            float4 w0 = *(const float4*)&Ws[k][q0];
            float4 w1 = *(const float4*)&Ws[k][q0 + 4];
            float xr[4] = {xv.x, xv.y, xv.z, xv.w};
            float wr[8] = {w0.x, w0.y, w0.z, w0.w, w1.x, w1.y, w1.z, w1.w};
#pragma unroll
            for (int r = 0; r < 4; ++r)
#pragma unroll
                for (int c = 0; c < 8; ++c)
                    acc[r][c] = fmaf(xr[r], wr[c], acc[r][c]);
        }
        __syncthreads();
    }

    // epilogue: store C + fused alpha reduction
    int c0 = cg * 8;
    int h = cg >> 2;  // all 8 cols within one head
    float as8[8], ad8[8];
#pragma unroll
    for (int c = 0; c < 8; ++c) { as8[c] = a_src[c0 + c]; ad8[c] = a_dst[c0 + c]; }
    float vs[4], vd[4];
#pragma unroll
    for (int r = 0; r < 4; ++r) {
        float s_ = 0.f, d_ = 0.f;
#pragma unroll
        for (int c = 0; c < 8; ++c) {
            s_ = fmaf(acc[r][c], as8[c], s_);
            d_ = fmaf(acc[r][c], ad8[c], d_);
        }
        vs[r] = s_; vd[r] = d_;
    }
#pragma unroll
    for (int r = 0; r < 4; ++r) {
        int gr = n0 + rg * 4 + r;
        if (gr < n) {
            *(float4*)&xw[(size_t)gr * 128 + c0] =
                make_float4(acc[r][0], acc[r][1], acc[r][2], acc[r][3]);
            *(float4*)&xw[(size_t)gr * 128 + c0 + 4] =
                make_float4(acc[r][4], acc[r][5], acc[r][6], acc[r][7]);
        }
    }
    // reduce alpha partials across the 4 lanes sharing (rg, h): lanes t^1, t^2
#pragma unroll
    for (int r = 0; r < 4; ++r) {
        vs[r] += __shfl_xor(vs[r], 1); vs[r] += __shfl_xor(vs[r], 2);
        vd[r] += __shfl_xor(vd[r], 1); vd[r] += __shfl_xor(vd[r], 2);
    }
    if ((t & 3) == 0) {
#pragma unroll
        for (int r = 0; r < 4; ++r) {
            int gr = n0 + rg * 4 + r;
            if (gr < n) { asrc[gr * 4 + h] = vs[r]; adst[gr * 4 + h] = vd[r]; }
        }
    }
}

// Aggregate v3: one 64-lane wave per dst node, zero LDS / zero barriers.
// Logit phase: 16 edges x 4 heads (lane = jj*4 + h4), online-softmax state
// (m, wsum) per-lane, chunk max/sum via __shfl_xor over the 16-lane head group.
// Gather phase: lane l owns channels 2l,2l+1 (head hA = l>>4); one float2 load
// per lane per edge = exactly one 512B row per instruction; weight broadcast
// via __shfl. Self-loop folded analytically (m=e_self, wsum=1, acc=xw[i]).
__global__ __launch_bounds__(256)
void aggregate_v3(const float* __restrict__ xw, const float* __restrict__ asrc,
                  const float* __restrict__ adst, const int* __restrict__ col,
                  const int* __restrict__ rs, const float* __restrict__ bias,
                  float* __restrict__ out, int n) {
    int l = threadIdx.x & 63;
    int i = (blockIdx.x * 256 + threadIdx.x) >> 6;  // wave-uniform node id
    if (i >= n) return;
    int h4 = l & 3;
    int jj = l >> 2;
    int hA = l >> 4;
    int beg = rs[i], end = rs[i + 1];
    float ad = adst[i * 4 + h4];
    float m = lrelu(asrc[i * 4 + h4] + ad);  // self-loop logit
    float wsum = 1.f;
    float2 acc = *(const float2*)&xw[(size_t)i * 128 + 2 * l];

    for (int ce = beg; ce < end; ce += 16) {
        int nc = end - ce; if (nc > 16) nc = 16;
        float e = -3.0e38f;
        if (jj < nc) {
            int s = col[ce + jj];
            e = lrelu(asrc[s * 4 + h4] + ad);
        }
        // chunk max per head (16-lane group l ≡ h4 mod 4)
        float mv = e;
        mv = fmaxf(mv, __shfl_xor(mv, 4));
        mv = fmaxf(mv, __shfl_xor(mv, 8));
        mv = fmaxf(mv, __shfl_xor(mv, 16));
        mv = fmaxf(mv, __shfl_xor(mv, 32));
        float newm = fmaxf(m, mv);
        float sc = __expf(m - newm);
        float wv = __expf(e - newm);  // invalid lanes -> exp(-huge) = 0
        float sv = wv;
        sv += __shfl_xor(sv, 4);
        sv += __shfl_xor(sv, 8);
        sv += __shfl_xor(sv, 16);
        sv += __shfl_xor(sv, 32);
        wsum = wsum * sc + sv;
        m = newm;
        // gather
        float scA = __shfl(sc, hA);
        acc.x *= scA; acc.y *= scA;
#pragma unroll
        for (int j = 0; j < 16; ++j) {
            if (j >= nc) break;
            int sj = __builtin_amdgcn_readfirstlane(col[ce + j]);  // uniform row
            float wg = __shfl(wv, j * 4 + hA);
            float2 v = *(const float2*)&xw[(size_t)sj * 128 + 2 * l];
            acc.x = fmaf(wg, v.x, acc.x);
            acc.y = fmaf(wg, v.y, acc.y);
        }
    }
    float wsA = __shfl(wsum, hA);
    float inv = 1.f / wsA;
    float2 bv = *(const float2*)&bias[2 * l];
    float2 r;
    r.x = elu(acc.x * inv + bv.x);
    r.y = elu(acc.y * inv + bv.y);
    *(float2*)&out[(size_t)i * 128 + 2 * l] = r;
}

// out[i] = sum_t h[i,t]*Wr[t] + br ; one node per 64-lane wave, 4 nodes/block
__global__ __launch_bounds__(256)
void head_kernel(const float* __restrict__ hin, const float* __restrict__ Wr,
                 const float* __restrict__ br, float* __restrict__ out, int n) {
    int tid = threadIdx.x;
    int i = blockIdx.x * 4 + (tid >> 6);
    if (i >= n) return;
    int l = tid & 63;
    float v = hin[(size_t)i * 128 + l] * Wr[l] + hin[(size_t)i * 128 + 64 + l] * Wr[64 + l];
#pragma unroll
    for (int off = 32; off > 0; off >>= 1) v += __shfl_xor(v, off);
    if (l == 0) out[i] = v + br[0];
}

extern "C" void kernel_launch(void* const* d_in, const int* in_sizes, int n_in,
                              void* d_out, int out_size, void* d_ws, size_t ws_size,
                              hipStream_t stream) {
    const float* x   = (const float*)d_in[0];
    const int*   ei  = (const int*)d_in[1];
    const float* W0  = (const float*)d_in[2];
    const float* as0 = (const float*)d_in[3];
    const float* ad0 = (const float*)d_in[4];
    const float* b0  = (const float*)d_in[5];
    const float* W1  = (const float*)d_in[6];
    const float* as1 = (const float*)d_in[7];
    const float* ad1 = (const float*)d_in[8];
    const float* b1  = (const float*)d_in[9];
    const float* Wr  = (const float*)d_in[10];
    const float* br  = (const float*)d_in[11];
    float* out = (float*)d_out;

    const int N = in_sizes[0] / 128;
    const int E = in_sizes[1] / 2;

    char* w = (char*)d_ws;
    size_t off = 0;
    auto alloc = [&](size_t bytes) -> void* {
        void* p = w + off;
        off += (bytes + 255) & ~size_t(255);
        return p;
    };
    float* bufA   = (float*)alloc((size_t)N * 128 * 4);  // xw
    float* bufB   = (float*)alloc((size_t)N * 128 * 4);  // layer output h
    float* asrc   = (float*)alloc((size_t)N * 4 * 4);
    float* adst   = (float*)alloc((size_t)N * 4 * 4);
    int*   deg    = (int*)alloc((size_t)N * 4);
    int*   rs     = (int*)alloc((size_t)(N + 1) * 4);
    int*   cursor = (int*)alloc((size_t)N * 4);
    int*   col    = (int*)alloc((size_t)E * 4);

    // CSR build (shared by both layers)
    zero_i32<<<(N + 255) / 256, 256, 0, stream>>>(deg, N);
    hist_kernel<<<(E + 255) / 256, 256, 0, stream>>>(ei, deg, E);
    scan_kernel<<<1, 1024, 0, stream>>>(deg, rs, cursor, N);
    scatter_kernel<<<(E + 255) / 256, 256, 0, stream>>>(ei, cursor, col, E);

    int gblk = (N + 63) / 64;
    int ablk = (N + 3) / 4;
    // Layer 0
    gemm_alpha_v4<<<gblk, 256, 0, stream>>>(x, W0, as0, ad0, bufA, asrc, adst, N);
    aggregate_v3<<<ablk, 256, 0, stream>>>(bufA, asrc, adst, col, rs, b0, bufB, N);
    // Layer 1
    gemm_alpha_v4<<<gblk, 256, 0, stream>>>(bufB, W1, as1, ad1, bufA, asrc, adst, N);
    aggregate_v3<<<ablk, 256, 0, stream>>>(bufA, asrc, adst, col, rs, b1, bufB, N);
    // Regression head
    head_kernel<<<(N + 3) / 4, 256, 0, stream>>>(bufB, Wr, br, out, N);
}

// Round 4
// 394.795 us; speedup vs baseline: 2.1292x; 1.3817x over previous
//
#include <hip/hip_runtime.h>
#include <hip/hip_bf16.h>

#define DEV __device__ __forceinline__

DEV float lrelu(float x) { return x > 0.f ? x : 0.2f * x; }
DEV float elu(float x)   { return x > 0.f ? x : __expf(x) - 1.f; }

__global__ void hist_kernel(const int* __restrict__ ei, int* __restrict__ deg, int E) {
    int e = blockIdx.x * 256 + threadIdx.x;
    if (e < E) atomicAdd(&deg[ei[E + e]], 1);
}

// Phase A: per-block sums of deg (512 elems / 256-thread block)
__global__ __launch_bounds__(256)
void block_sum_kernel(const int* __restrict__ deg, int* __restrict__ bsum, int n) {
    int b = blockIdx.x, t = threadIdx.x;
    int i0 = b * 512 + 2 * t;
    int d0 = (i0 < n) ? deg[i0] : 0;
    int d1 = (i0 + 1 < n) ? deg[i0 + 1] : 0;
    int s = d0 + d1;
#pragma unroll
    for (int off = 32; off > 0; off >>= 1) s += __shfl_xor(s, off);
    __shared__ int wsum[4];
    if ((t & 63) == 0) wsum[t >> 6] = s;
    __syncthreads();
    if (t == 0) bsum[b] = wsum[0] + wsum[1] + wsum[2] + wsum[3];
}

// Phase B: one block scans the <=256 block sums (exclusive) + writes rs[n]=E
__global__ __launch_bounds__(256)
void scan_bsums_kernel(const int* __restrict__ bsum, int* __restrict__ bpre,
                       int* __restrict__ rs, int nblk, int n, int E) {
    __shared__ int ps[256];
    int t = threadIdx.x;
    int v = (t < nblk) ? bsum[t] : 0;
    ps[t] = v;
    __syncthreads();
    for (int off = 1; off < 256; off <<= 1) {
        int u = (t >= off) ? ps[t - off] : 0;
        __syncthreads();
        ps[t] += u;
        __syncthreads();
    }
    if (t < nblk) bpre[t] = ps[t] - v;  // exclusive prefix of block sums
    if (t == 0) rs[n] = E;              // total degree == E analytically
}

// Phase C: per-block local scan + block prefix -> row_start & cursor
__global__ __launch_bounds__(256)
void scan_emit_kernel(const int* __restrict__ deg, const int* __restrict__ bpre,
                      int* __restrict__ rs, int* __restrict__ cursor, int n) {
    __shared__ int ps[256];
    int b = blockIdx.x, t = threadIdx.x;
    int i0 = b * 512 + 2 * t;
    int d0 = (i0 < n) ? deg[i0] : 0;
    int d1 = (i0 + 1 < n) ? deg[i0 + 1] : 0;
    int s = d0 + d1;
    ps[t] = s;
    __syncthreads();
    for (int off = 1; off < 256; off <<= 1) {
        int u = (t >= off) ? ps[t - off] : 0;
        __syncthreads();
        ps[t] += u;
        __syncthreads();
    }
    int excl = ps[t] - s + bpre[b];
    if (i0 < n)     { rs[i0] = excl;          cursor[i0] = excl; }
    if (i0 + 1 < n) { rs[i0 + 1] = excl + d0; cursor[i0 + 1] = excl + d0; }
}

__global__ void scatter_kernel(const int* __restrict__ ei, int* __restrict__ cursor,
                               int* __restrict__ col, int E) {
    int e = blockIdx.x * 256 + threadIdx.x;
    if (e < E) {
        int s = ei[e], d = ei[E + e];
        int pos = atomicAdd(&cursor[d], 1);
        col[pos] = s;
    }
}

// GEMM v4: 256 threads, 64-node x 128-col tile, K staged in chunks of 32.
// Thread (rg=t>>4, cg=t&15) computes rows rg*4..+3 x cols cg*8..+7 (acc 4x8).
__global__ __launch_bounds__(256)
void gemm_alpha_v4(const float* __restrict__ X, const float* __restrict__ W,
                   const float* __restrict__ a_src, const float* __restrict__ a_dst,
                   float* __restrict__ xw, float* __restrict__ asrc,
                   float* __restrict__ adst, int n) {
    __shared__ float Xs[32][68];
    __shared__ float Ws[32][132];
    int t = threadIdx.x;
    int n0 = blockIdx.x * 64;
    int rg = t >> 4;
    int cg = t & 15;
    int q0 = cg * 8 + ((cg >= 8) ? 4 : 0);
    float acc[4][8];
#pragma unroll
    for (int r = 0; r < 4; ++r)
#pragma unroll
        for (int c = 0; c < 8; ++c) acc[r][c] = 0.f;

    for (int k0 = 0; k0 < 128; k0 += 32) {
#pragma unroll
        for (int it = 0; it < 2; ++it) {
            int idx = t + it * 256;
            int row = idx >> 3, kq = idx & 7;
            int gr = n0 + row;
            float4 v = make_float4(0.f, 0.f, 0.f, 0.f);
            if (gr < n) v = *(const float4*)&X[(size_t)gr * 128 + k0 + kq * 4];
            Xs[kq * 4 + 0][row] = v.x;
            Xs[kq * 4 + 1][row] = v.y;
            Xs[kq * 4 + 2][row] = v.z;
            Xs[kq * 4 + 3][row] = v.w;
        }
#pragma unroll
        for (int it = 0; it < 4; ++it) {
            int idx = t + it * 256;
            int k = idx >> 5, cq = idx & 31;
            float4 v = *(const float4*)&W[(size_t)(k0 + k) * 128 + cq * 4];
            *(float4*)&Ws[k][cq * 4 + ((cq >= 16) ? 4 : 0)] = v;
        }
        __syncthreads();
#pragma unroll 4
        for (int k = 0; k < 32; ++k) {
            float4 xv = *(const float4*)&Xs[k][rg * 4];
            float4 w0 = *(const float4*)&Ws[k][q0];
            float4 w1 = *(const float4*)&Ws[k][q0 + 4];
            float xr[4] = {xv.x, xv.y, xv.z, xv.w};
            float wr[8] = {w0.x, w0.y, w0.z, w0.w, w1.x, w1.y, w1.z, w1.w};
#pragma unroll
            for (int r = 0; r < 4; ++r)
#pragma unroll
                for (int c = 0; c < 8; ++c)
                    acc[r][c] = fmaf(xr[r], wr[c], acc[r][c]);
        }
        __syncthreads();
    }

    int c0 = cg * 8;
    int h = cg >> 2;
    float as8[8], ad8[8];
#pragma unroll
    for (int c = 0; c < 8; ++c) { as8[c] = a_src[c0 + c]; ad8[c] = a_dst[c0 + c]; }
    float vs[4], vd[4];
#pragma unroll
    for (int r = 0; r < 4; ++r) {
        float s_ = 0.f, d_ = 0.f;
#pragma unroll
        for (int c = 0; c < 8; ++c) {
            s_ = fmaf(acc[r][c], as8[c], s_);
            d_ = fmaf(acc[r][c], ad8[c], d_);
        }
        vs[r] = s_; vd[r] = d_;
    }
#pragma unroll
    for (int r = 0; r < 4; ++r) {
        int gr = n0 + rg * 4 + r;
        if (gr < n) {
            *(float4*)&xw[(size_t)gr * 128 + c0] =
                make_float4(acc[r][0], acc[r][1], acc[r][2], acc[r][3]);
            *(float4*)&xw[(size_t)gr * 128 + c0 + 4] =
                make_float4(acc[r][4], acc[r][5], acc[r][6], acc[r][7]);
        }
    }
#pragma unroll
    for (int r = 0; r < 4; ++r) {
        vs[r] += __shfl_xor(vs[r], 1); vs[r] += __shfl_xor(vs[r], 2);
        vd[r] += __shfl_xor(vd[r], 1); vd[r] += __shfl_xor(vd[r], 2);
    }
    if ((t & 3) == 0) {
#pragma unroll
        for (int r = 0; r < 4; ++r) {
            int gr = n0 + rg * 4 + r;
            if (gr < n) { asrc[gr * 4 + h] = vs[r]; adst[gr * 4 + h] = vd[r]; }
        }
    }
}

// Aggregate v3b: one 64-lane wave per dst node, zero LDS / zero barriers.
// Gather src index via __shfl from the logit lanes (no col reload).
__global__ __launch_bounds__(256)
void aggregate_v3(const float* __restrict__ xw, const float* __restrict__ asrc,
                  const float* __restrict__ adst, const int* __restrict__ col,
                  const int* __restrict__ rs, const float* __restrict__ bias,
                  float* __restrict__ out, int n) {
    int l = threadIdx.x & 63;
    int i = (blockIdx.x * 256 + threadIdx.x) >> 6;  // wave-uniform node id
    if (i >= n) return;
    int h4 = l & 3;
    int jj = l >> 2;
    int hA = l >> 4;
    int beg = rs[i], end = rs[i + 1];
    float ad = adst[i * 4 + h4];
    float m = lrelu(asrc[i * 4 + h4] + ad);  // self-loop logit
    float wsum = 1.f;
    float2 acc = *(const float2*)&xw[(size_t)i * 128 + 2 * l];

    for (int ce = beg; ce < end; ce += 16) {
        int nc = end - ce; if (nc > 16) nc = 16;
        float e = -3.0e38f;
        int s = 0;
        if (jj < nc) {
            s = col[ce + jj];
            e = lrelu(asrc[s * 4 + h4] + ad);
        }
        float mv = e;
        mv = fmaxf(mv, __shfl_xor(mv, 4));
        mv = fmaxf(mv, __shfl_xor(mv, 8));
        mv = fmaxf(mv, __shfl_xor(mv, 16));
        mv = fmaxf(mv, __shfl_xor(mv, 32));
        float newm = fmaxf(m, mv);
        float sc = __expf(m - newm);
        float wv = __expf(e - newm);  // invalid lanes -> exp(-huge) = 0
        float sv = wv;
        sv += __shfl_xor(sv, 4);
        sv += __shfl_xor(sv, 8);
        sv += __shfl_xor(sv, 16);
        sv += __shfl_xor(sv, 32);
        wsum = wsum * sc + sv;
        m = newm;
        float scA = __shfl(sc, hA);
        acc.x *= scA; acc.y *= scA;
#pragma unroll
        for (int j = 0; j < 16; ++j) {
            if (j >= nc) break;
            int sj = __shfl(s, j * 4);            // lane 4j holds col[ce+j]
            float wg = __shfl(wv, j * 4 + hA);
            float2 v = *(const float2*)&xw[(size_t)sj * 128 + 2 * l];
            acc.x = fmaf(wg, v.x, acc.x);
            acc.y = fmaf(wg, v.y, acc.y);
        }
    }
    float wsA = __shfl(wsum, hA);
    float inv = 1.f / wsA;
    float2 bv = *(const float2*)&bias[2 * l];
    float2 r;
    r.x = elu(acc.x * inv + bv.x);
    r.y = elu(acc.y * inv + bv.y);
    *(float2*)&out[(size_t)i * 128 + 2 * l] = r;
}

// out[i] = sum_t h[i,t]*Wr[t] + br ; one node per 64-lane wave, 4 nodes/block
__global__ __launch_bounds__(256)
void head_kernel(const float* __restrict__ hin, const float* __restrict__ Wr,
                 const float* __restrict__ br, float* __restrict__ out, int n) {
    int tid = threadIdx.x;
    int i = blockIdx.x * 4 + (tid >> 6);
    if (i >= n) return;
    int l = tid & 63;
    float v = hin[(size_t)i * 128 + l] * Wr[l] + hin[(size_t)i * 128 + 64 + l] * Wr[64 + l];
#pragma unroll
    for (int off = 32; off > 0; off >>= 1) v += __shfl_xor(v, off);
    if (l == 0) out[i] = v + br[0];
}

extern "C" void kernel_launch(void* const* d_in, const int* in_sizes, int n_in,
                              void* d_out, int out_size, void* d_ws, size_t ws_size,
                              hipStream_t stream) {
    const float* x   = (const float*)d_in[0];
    const int*   ei  = (const int*)d_in[1];
    const float* W0  = (const float*)d_in[2];
    const float* as0 = (const float*)d_in[3];
    const float* ad0 = (const float*)d_in[4];
    const float* b0  = (const float*)d_in[5];
    const float* W1  = (const float*)d_in[6];
    const float* as1 = (const float*)d_in[7];
    const float* ad1 = (const float*)d_in[8];
    const float* b1  = (const float*)d_in[9];
    const float* Wr  = (const float*)d_in[10];
    const float* br  = (const float*)d_in[11];
    float* out = (float*)d_out;

    const int N = in_sizes[0] / 128;
    const int E = in_sizes[1] / 2;

    char* w = (char*)d_ws;
    size_t off = 0;
    auto alloc = [&](size_t bytes) -> void* {
        void* p = w + off;
        off += (bytes + 255) & ~size_t(255);
        return p;
    };
    float* bufA   = (float*)alloc((size_t)N * 128 * 4);  // xw
    float* bufB   = (float*)alloc((size_t)N * 128 * 4);  // layer output h
    float* asrc   = (float*)alloc((size_t)N * 4 * 4);
    float* adst   = (float*)alloc((size_t)N * 4 * 4);
    int*   deg    = (int*)alloc((size_t)N * 4);
    int*   rs     = (int*)alloc((size_t)(N + 1) * 4);
    int*   cursor = (int*)alloc((size_t)N * 4);
    int*   col    = (int*)alloc((size_t)E * 4);
    int*   bsum   = (int*)alloc(1024 * 4);
    int*   bpre   = (int*)alloc(1024 * 4);

    const int nblk = (N + 511) / 512;  // 98 for N=50000 (must be <= 256)

    // CSR build (shared by both layers)
    hipMemsetAsync(deg, 0, (size_t)N * 4, stream);
    hist_kernel<<<(E + 255) / 256, 256, 0, stream>>>(ei, deg, E);
    block_sum_kernel<<<nblk, 256, 0, stream>>>(deg, bsum, N);
    scan_bsums_kernel<<<1, 256, 0, stream>>>(bsum, bpre, rs, nblk, N, E);
    scan_emit_kernel<<<nblk, 256, 0, stream>>>(deg, bpre, rs, cursor, N);
    scatter_kernel<<<(E + 255) / 256, 256, 0, stream>>>(ei, cursor, col, E);

    int gblk = (N + 63) / 64;
    int ablk = (N + 3) / 4;
    // Layer 0
    gemm_alpha_v4<<<gblk, 256, 0, stream>>>(x, W0, as0, ad0, bufA, asrc, adst, N);
    aggregate_v3<<<ablk, 256, 0, stream>>>(bufA, asrc, adst, col, rs, b0, bufB, N);
    // Layer 1
    gemm_alpha_v4<<<gblk, 256, 0, stream>>>(bufB, W1, as1, ad1, bufA, asrc, adst, N);
    aggregate_v3<<<ablk, 256, 0, stream>>>(bufA, asrc, adst, col, rs, b1, bufB, N);
    // Regression head
    head_kernel<<<(N + 3) / 4, 256, 0, stream>>>(bufB, Wr, br, out, N);
}